// Round 22
// baseline (63.698 us; speedup 1.0000x reference)
//
#include <hip/hip_runtime.h>

typedef __attribute__((ext_vector_type(4))) float f32x4;
typedef __attribute__((ext_vector_type(4))) unsigned u32x4;
typedef __attribute__((ext_vector_type(8))) short bf16x8;

constexpr int Asz = 32, Isz = 256, Osz = 256;
constexpr int NI = 8;                  // iterations of 64-row super-tiles

// packed f32x2 -> bf16x2 (RNE); no builtin on gfx950
__device__ inline unsigned cvtpk(float lo, float hi) {
    unsigned r;
    asm("v_cvt_pk_bf16_f32 %0, %1, %2" : "=v"(r) : "v"(lo), "v"(hi));
    return r;
}

// ---------------------------------------------------------------------------
// r22: 64-row iterations, SINGLE-buffered sA (32 KB; LDS = 160 KB exact).
// Per kt each wave reads 4 A-frags + 2 B-frags, 8 MFMAs -> LDS reads/CU drop
// 4096 -> 3072 (B amortized over 4 sub-tiles). Sync = two RAW s_barriers per
// iteration: fill-side preceded by lgkmcnt(0) only (ds_write visibility);
// compute-side needs no wait (read results consumed by MFMAs). Stores and
// fill-loads are NEVER waited on -- no vmcnt (counted or drained) anywhere;
// load->use ordering stays compiler-tracked (r20/r21's proven-safe scheme).
// 256 blocks (1/CU), 512 threads = 8 waves; reg-staged bf16 A fill:
// 8 pinned f32x4 loads/lane issued at compute-phase top (64 KB/CU in flight).
// ---------------------------------------------------------------------------
__global__ __launch_bounds__(512, 2) void al_gemm(const float* __restrict__ x,
                                                  const float* __restrict__ wsrc,
                                                  const float* __restrict__ bias,
                                                  float* __restrict__ out)
{
    __shared__ char sA[32768];      // 64 rows x 512B bf16, chunk-XOR swizzled
    __shared__ char sB[131072];     // packed B, fragment-linear

    // 256 blocks: xcd p&7 hosts a in {4k..4k+3}; rowgroup p>>5 -> 512 rows.
    const int p  = blockIdx.x;
    const int a  = (p & 7) * 4 + ((p >> 3) & 3);
    const int b0 = (p >> 5) * 512;

    const int t    = threadIdx.x;
    const int w    = t >> 6;          // wave 0..7
    const int lane = t & 63;
    const int llo  = lane & 15, lhi = lane >> 4;

    // ---- A fill: lane covers row lr = 8w + (lane>>3), f32 cols (lane&7)*32..+32
    // (8 f32x4 loads -> 16 cvt_pk -> 4 ds_write_b128 at XOR-swizzled chunks).
    const int lr = 8 * w + (lane >> 3);
    const int c0 = (lane & 7) * 4;         // first of this lane's 4 bf16-chunks
    const float* xrow = x + ((size_t)(b0 + lr) * Asz + a) * Isz + (lane & 7) * 32;
    int wadr[4];
#pragma unroll
    for (int j = 0; j < 4; ++j)
        wadr[j] = lr * 512 + (((c0 + j) ^ (lr & 31)) << 4);

    f32x4 L[8];                            // in-flight fill regs (32 VGPR)
#pragma unroll
    for (int j = 0; j < 8; ++j) L[j] = *(const f32x4*)(xrow + j * 4);
    asm volatile("" : "+v"(L[0]), "+v"(L[1]), "+v"(L[2]), "+v"(L[3]),
                      "+v"(L[4]), "+v"(L[5]), "+v"(L[6]), "+v"(L[7]));

    // ---- pack w[a] f32 -> sB bf16, fragment-linear — COALESCED (r19):
    // slot s = i*512+t -> 8 contiguous f32 at wa+s*8 = lane-slot of frag:
    // o = s>>5, kt = (s>>2)&7, nf = s>>9, lane_ = (o&15) | ((s&3)<<4).
    {
        const float* wa = wsrc + (size_t)a * (Osz * Isz);
#pragma unroll
        for (int i = 0; i < 16; ++i) {
            const int s     = i * 512 + t;
            const int o     = s >> 5;
            const int kt    = (s >> 2) & 7;
            const int nf    = s >> 9;
            const int lane_ = (o & 15) | ((s & 3) << 4);
            f32x4 lo = *(const f32x4*)(wa + (size_t)s * 8);
            f32x4 hi = *(const f32x4*)(wa + (size_t)s * 8 + 4);
            union { bf16x8 v; unsigned u[4]; } r;
            r.u[0] = cvtpk(lo[0], lo[1]); r.u[1] = cvtpk(lo[2], lo[3]);
            r.u[2] = cvtpk(hi[0], hi[1]); r.u[3] = cvtpk(hi[2], hi[3]);
            *(bf16x8*)&sB[(((kt * 16 + nf) * 64) + lane_) * 16] = r.v;
        }
    }

    // bias in exactly 2 VGPRs (r13 invariant)
    const float bv0 = bias[a * Osz + w * 32 + llo];
    const float bv1 = bias[a * Osz + w * 32 + 16 + llo];

    for (int i = 0; i < NI; ++i) {
        // ---- phase A: cvt + write fill(i) into sA ----
#pragma unroll
        for (int j = 0; j < 4; ++j) {
            u32x4 pk;
            pk[0] = cvtpk(L[2*j][0],   L[2*j][1]);
            pk[1] = cvtpk(L[2*j][2],   L[2*j][3]);
            pk[2] = cvtpk(L[2*j+1][0], L[2*j+1][1]);
            pk[3] = cvtpk(L[2*j+1][2], L[2*j+1][3]);
            *(u32x4*)&sA[wadr[j]] = pk;
        }
        asm volatile("s_waitcnt lgkmcnt(0)" ::: "memory");  // ds_writes visible
        __builtin_amdgcn_s_barrier();                       // no vmem drain!

        // ---- phase B: issue next fill loads, compute, store ----
        if (i < NI - 1) {
            const float* nx = xrow + (size_t)(i + 1) * (64 * Asz * Isz);
#pragma unroll
            for (int j = 0; j < 8; ++j) L[j] = *(const f32x4*)(nx + j * 4);
            asm volatile("" : "+v"(L[0]), "+v"(L[1]), "+v"(L[2]), "+v"(L[3]),
                              "+v"(L[4]), "+v"(L[5]), "+v"(L[6]), "+v"(L[7]));
        }

        f32x4 acc[4][2];
#pragma unroll
        for (int m = 0; m < 4; ++m) { acc[m][0] = (f32x4)(bv0); acc[m][1] = (f32x4)(bv1); }

        __builtin_amdgcn_s_setprio(1);
#pragma unroll
        for (int kt = 0; kt < 8; ++kt) {
            const int c = kt * 4 + lhi;
            const bf16x8 bF0 = *(const bf16x8*)&sB[(kt * 16 + 2 * w) * 1024 + lane * 16];
            const bf16x8 bF1 = *(const bf16x8*)&sB[(kt * 16 + 2 * w + 1) * 1024 + lane * 16];
#pragma unroll
            for (int m = 0; m < 4; ++m) {
                const int row = m * 16 + llo;
                const bf16x8 aF = *(const bf16x8*)&sA[row * 512 + ((c ^ (row & 31)) << 4)];
                acc[m][0] = __builtin_amdgcn_mfma_f32_16x16x32_bf16(aF, bF0, acc[m][0], 0, 0, 0);
                acc[m][1] = __builtin_amdgcn_mfma_f32_16x16x32_bf16(aF, bF1, acc[m][1], 0, 0, 0);
            }
        }
        __builtin_amdgcn_s_setprio(0);

        // stores: D[row = i*64 + m*16 + lhi*4 + r2][col = w*32 + {0,16} + llo]
#pragma unroll
        for (int m = 0; m < 4; ++m) {
            const int trow = b0 + i * 64 + m * 16 + lhi * 4;
            float* op = out + ((size_t)trow * Asz + a) * Osz + w * 32 + llo;
#pragma unroll
            for (int r2 = 0; r2 < 4; ++r2) {
                op[(size_t)r2 * Asz * Osz]      = acc[m][0][r2];
                op[(size_t)r2 * Asz * Osz + 16] = acc[m][1][r2];
            }
        }

        // end-of-iteration barrier: all waves' reads of sA are consumed
        // (lgkm drained by use) -> safe to overwrite sA next iteration.
        __builtin_amdgcn_s_barrier();
    }
}

extern "C" void kernel_launch(void* const* d_in, const int* in_sizes, int n_in,
                              void* d_out, int out_size, void* d_ws, size_t ws_size,
                              hipStream_t stream) {
    const float* x    = (const float*)d_in[0];
    const float* w    = (const float*)d_in[1];
    const float* bias = (const float*)d_in[2];
    float* out        = (float*)d_out;
    al_gemm<<<dim3(256), dim3(512), 0, stream>>>(x, w, bias, out);
}

// Round 23
// 56.983 us; speedup vs baseline: 1.1179x; 1.1179x over previous
//
#include <hip/hip_runtime.h>

typedef __attribute__((ext_vector_type(4))) float f32x4;
typedef __attribute__((ext_vector_type(2))) unsigned u32x2;
typedef __attribute__((ext_vector_type(8))) short bf16x8;

constexpr int Bsz = 4096, Asz = 32, Isz = 256, Osz = 256;
constexpr int NI = 16;                 // iterations of 32-row super-tiles

// packed f32x2 -> bf16x2 (RNE); no builtin on gfx950
__device__ inline unsigned cvtpk(float lo, float hi) {
    unsigned r;
    asm("v_cvt_pk_bf16_f32 %0, %1, %2" : "=v"(r) : "v"(lo), "v"(hi));
    return r;
}

// ---------------------------------------------------------------------------
// r23 = r21 (proven 58.8us PASS) with the per-iteration __syncthreads()
// (which drains vmcnt(0): all 16 stores + load residue, every iteration)
// replaced by lgkmcnt(0) + RAW s_barrier — stores and fill loads are never
// waited on; only ds_write visibility is fenced. No vmcnt anywhere (counted
// or drained). All load->use ordering stays compiler-tracked.
// Structure: 256 blocks (1/CU), 512 threads = 8 waves, LDS 160 KB exact
// (sA 2x16KB double-buffered bf16 + sB 128KB packed B). 2 tiles (32 rows)
// per iteration amortize B-reads; reg-staged bf16 A fill with pinned loads.
// ---------------------------------------------------------------------------
__global__ __launch_bounds__(512, 2) void al_gemm(const float* __restrict__ x,
                                                  const float* __restrict__ wsrc,
                                                  const float* __restrict__ bias,
                                                  float* __restrict__ out)
{
    __shared__ char sA[2][16384];   // 32 rows x 512B (bf16), chunk-XOR swizzled
    __shared__ char sB[131072];     // packed B, fragment-linear

    // 256 blocks: xcd p&7 hosts a in {4k..4k+3}; rowgroup p>>5 -> 512 rows.
    const int p  = blockIdx.x;
    const int a  = (p & 7) * 4 + ((p >> 3) & 3);
    const int b0 = (p >> 5) * 512;

    const int t    = threadIdx.x;
    const int w    = t >> 6;          // wave 0..7
    const int lane = t & 63;
    const int llo  = lane & 15, lhi = lane >> 4;

    // ---- A fill (reg-staged): wave w covers super-tile-local rows 4w..4w+3.
    // Lane holds f32 k = lane*4..+3 of its row -> 2 cvt_pk -> ds_write_b64 at
    // swizzled chunk ((lane>>1)^row)*16 + (lane&1)*8.
    const float* fs[4];
    int wadr[4];
#pragma unroll
    for (int j = 0; j < 4; ++j) {
        const int lr = 4 * w + j;
        fs[j]   = x + ((size_t)(b0 + lr) * Asz + a) * Isz + lane * 4;
        wadr[j] = lr * 512 + (((lane >> 1) ^ lr) << 4) + (lane & 1) * 8;
    }

    f32x4 L[4];                       // in-flight fill registers (16 VGPR)
#pragma unroll
    for (int j = 0; j < 4; ++j) L[j] = *(const f32x4*)fs[j];
    asm volatile("" : "+v"(L[0]), "+v"(L[1]), "+v"(L[2]), "+v"(L[3]));

    // ---- pack w[a] f32 -> sB bf16, fragment-linear — COALESCED (r19):
    // slot s = i*512+t -> 8 contiguous f32 at wa+s*8 = lane-slot of frag:
    // o = s>>5, kt = (s>>2)&7, nf = s>>9, lane_ = (o&15) | ((s&3)<<4).
    {
        const float* wa = wsrc + (size_t)a * (Osz * Isz);
#pragma unroll
        for (int i = 0; i < 16; ++i) {
            const int s     = i * 512 + t;
            const int o     = s >> 5;
            const int kt    = (s >> 2) & 7;
            const int nf    = s >> 9;
            const int lane_ = (o & 15) | ((s & 3) << 4);
            f32x4 lo = *(const f32x4*)(wa + (size_t)s * 8);
            f32x4 hi = *(const f32x4*)(wa + (size_t)s * 8 + 4);
            union { bf16x8 v; unsigned u[4]; } r;
            r.u[0] = cvtpk(lo[0], lo[1]); r.u[1] = cvtpk(lo[2], lo[3]);
            r.u[2] = cvtpk(hi[0], hi[1]); r.u[3] = cvtpk(hi[2], hi[3]);
            *(bf16x8*)&sB[(((kt * 16 + nf) * 64) + lane_) * 16] = r.v;
        }
    }

    const float bv0 = bias[a * Osz + w * 32 + llo];
    const float bv1 = bias[a * Osz + w * 32 + 16 + llo];

    // write L(0) into sA[0]
#pragma unroll
    for (int j = 0; j < 4; ++j)
        *(u32x2*)&sA[0][wadr[j]] = (u32x2){cvtpk(L[j][0], L[j][1]), cvtpk(L[j][2], L[j][3])};

    __syncthreads();   // one-time full drain: sA[0] + sB visible

    // compute-side A addrs: tile0 row = llo, tile1 row = llo+16;
    // chunk c = kt*4+lhi read at (c ^ row)*16.
    const int lr1 = llo + 16;

    for (int tn = 0; tn < NI; ++tn) {
        if (tn < NI - 1) {             // issue fill(tn+1); hides under compute
            const size_t o_ = (size_t)(tn + 1) * (32 * Asz * Isz);
#pragma unroll
            for (int j = 0; j < 4; ++j) L[j] = *(const f32x4*)(fs[j] + o_);
            asm volatile("" : "+v"(L[0]), "+v"(L[1]), "+v"(L[2]), "+v"(L[3]));
        }

        const char* As = &sA[tn & 1][0];
        f32x4 acc00 = (f32x4)(bv0), acc01 = (f32x4)(bv1);   // tile0
        f32x4 acc10 = (f32x4)(bv0), acc11 = (f32x4)(bv1);   // tile1
        __builtin_amdgcn_s_setprio(1);
#pragma unroll
        for (int kt = 0; kt < 8; ++kt) {
            const int c = kt * 4 + lhi;
            const bf16x8 aF0 = *(const bf16x8*)&As[llo * 512 + ((c ^ llo) << 4)];
            const bf16x8 aF1 = *(const bf16x8*)&As[lr1 * 512 + ((c ^ lr1) << 4)];
            const bf16x8 bF0 = *(const bf16x8*)&sB[(kt * 16 + 2 * w) * 1024 + lane * 16];
            const bf16x8 bF1 = *(const bf16x8*)&sB[(kt * 16 + 2 * w + 1) * 1024 + lane * 16];
            acc00 = __builtin_amdgcn_mfma_f32_16x16x32_bf16(aF0, bF0, acc00, 0, 0, 0);
            acc01 = __builtin_amdgcn_mfma_f32_16x16x32_bf16(aF0, bF1, acc01, 0, 0, 0);
            acc10 = __builtin_amdgcn_mfma_f32_16x16x32_bf16(aF1, bF0, acc10, 0, 0, 0);
            acc11 = __builtin_amdgcn_mfma_f32_16x16x32_bf16(aF1, bF1, acc11, 0, 0, 0);
        }
        __builtin_amdgcn_s_setprio(0);

        // stores: tile0 rows b0+tn*32+lhi*4+r2, tile1 +16; NEVER waited on
        const int trow = b0 + tn * 32 + lhi * 4;
        float* op0 = out + ((size_t)trow * Asz + a) * Osz + w * 32 + llo;
        float* op1 = op0 + (size_t)16 * Asz * Osz;
#pragma unroll
        for (int r2 = 0; r2 < 4; ++r2) {
            op0[(size_t)r2 * Asz * Osz]      = acc00[r2];
            op0[(size_t)r2 * Asz * Osz + 16] = acc01[r2];
            op1[(size_t)r2 * Asz * Osz]      = acc10[r2];
            op1[(size_t)r2 * Asz * Osz + 16] = acc11[r2];
        }

        if (tn < NI - 1) {             // cvt + write fill into the other buffer
            char* Ad = &sA[(tn + 1) & 1][0];
#pragma unroll
            for (int j = 0; j < 4; ++j)
                *(u32x2*)&Ad[wadr[j]] = (u32x2){cvtpk(L[j][0], L[j][1]), cvtpk(L[j][2], L[j][3])};
        }

        // ds_writes visible to all; stores/loads NOT drained (raw barrier).
        // Reads of the old buffer are provably consumed (acc -> stores).
        asm volatile("s_waitcnt lgkmcnt(0)" ::: "memory");
        __builtin_amdgcn_s_barrier();
    }
}

extern "C" void kernel_launch(void* const* d_in, const int* in_sizes, int n_in,
                              void* d_out, int out_size, void* d_ws, size_t ws_size,
                              hipStream_t stream) {
    const float* x    = (const float*)d_in[0];
    const float* w    = (const float*)d_in[1];
    const float* bias = (const float*)d_in[2];
    float* out        = (float*)d_out;
    al_gemm<<<dim3(256), dim3(512), 0, stream>>>(x, w, bias, out);
}